// Round 8
// baseline (145.255 us; speedup 1.0000x reference)
//
#include <hip/hip_runtime.h>

// TorchPatchNN: unfold(7x7) -> NN argmin over 8100 keys (D=147) -> gather value -> fold mean.
// Round 13: register-starved latency bound. R8 (LDS-staged) ~= R12 (all-direct, 2x L2
//  traffic) at 71-72us => neither LDS nor L2 BW binds; the per-chunk dependency wall does:
//  16 frag loads must complete before the 233-cyc MFMA block, and 124 VGPR + 128 AGPR left
//  no room to prefetch chunk c+1. Fix: merge the two accumulators. Lo-planes now stored
//  UNSCALED (l = v-h, ~2^-12 magnitude, normal fp16) so all 3 MFMA passes accumulate into
//  ONE acc[4][4] (64 AGPR): acc += ah*bh + ah*bl + al*bh; epilogue = kn - 2*acc.
//  Freed 64 regs buy a 2-deep fragment double-buffer (statically indexed under the fully
//  unrolled chunk loop): chunk c+1's 16 loads issue BEFORE chunk c's MFMA block => each
//  wave self-covers L2 latency. Budget ~216 regs < 256 @ 2 blocks/CU.
//  Keep: barrier-free K-loop (R12), XCD swizzle, setprio, u64 epilogue, R11 k_fold.
//  Falsifiers: VGPR>256/spill => pipeline collapsed; dur unchanged at ~216 regs => theory
//  wrong, stub epilogue next round.

#define NQ 8100
#define NK 8100
#define DD 147
#define HO 90
#define IMG 96
#define NCH 5                 // K chunks of 32 (160 padded K)
#define CST 262144            // f16 per chunk plane: 512 groups x 512
#define ARRN (NCH * CST)      // f16 per array

typedef _Float16 half8 __attribute__((ext_vector_type(8)));
typedef float f32x4 __attribute__((ext_vector_type(4)));

// ---------------- prep: split Q/K into fp16 hi/lo (frag order) + key norms + init ---------
__global__ void k_prep(const float* __restrict__ query, const float* __restrict__ key,
                       _Float16* __restrict__ Qh, _Float16* __restrict__ Ql,
                       _Float16* __restrict__ Kh, _Float16* __restrict__ Kl,
                       float* __restrict__ kn, unsigned long long* __restrict__ fidx64) {
    const int bx = blockIdx.x;
    const bool isK = (blockIdx.y != 0);

    if (bx >= 640) {                      // fused k_kn region: 128 blocks on y==1
        if (!isK) return;
        int wave = threadIdx.x >> 6, lane = threadIdx.x & 63;
        int kb = ((bx - 640) * 4 + wave) * 16;
        for (int r = 0; r < 16; ++r) {
            int k = kb + r;
            float s = 0.f;
            if (k < NK)
                for (int d = lane; d < DD; d += 64) {
                    float v = key[k * DD + d];
                    s += v * v;
                }
#pragma unroll
            for (int off = 32; off; off >>= 1) s += __shfl_down(s, off, 64);
            if (lane == 0) {
                kn[k] = (k < NK) ? s : 1e30f;
                fidx64[k] = 0xFFFFFFFFFFFFFFFFull;   // ws re-poisoned every launch
            }
        }
        return;
    }

    int t = bx * 256 + threadIdx.x;             // 0 .. 163839 (ARRN/8)
    int c = t >> 15;                            // chunk
    int rem = t & 32767;                        // g*64 + lane
    int col = ((rem >> 6) << 4) + (rem & 15);   // g*16 + l15
    int quad = (rem >> 4) & 3;
    int kbase = c * 32 + quad * 8;

    float v[8];
#pragma unroll
    for (int j = 0; j < 8; ++j) {
        int k = kbase + j;
        float x = 0.f;
        if (k < DD && col < NQ) {
            if (isK) {
                x = key[col * DD + k];
            } else {
                int c3 = k / 49, r2 = k - 49 * c3;
                int rr = r2 / 7, ss = r2 - 7 * rr;
                int y = col / HO, xx = col - HO * y;
                x = query[(c3 * IMG + y + rr) * IMG + xx + ss];
            }
        }
        v[j] = x;
    }
    half8 h8, l8;
#pragma unroll
    for (int j = 0; j < 8; ++j) {
        _Float16 h = (_Float16)v[j];
        h8[j] = h;
        l8[j] = (_Float16)(v[j] - (float)h);   // UNSCALED lo (merged-acc scheme)
    }
    if (isK) {
        *(half8*)(Kh + t * 8) = h8;
        *(half8*)(Kl + t * 8) = l8;
    } else {
        *(half8*)(Qh + t * 8) = h8;
        *(half8*)(Ql + t * 8) = l8;
    }
}

// ---------------- main: merged-acc split-f16 MFMA Q.K^T + fused argmin ----------------
// Barrier-free K-loop, 2-deep fragment double-buffer, single acc[4][4].
__launch_bounds__(256, 2)
__global__ void k_nn(const _Float16* __restrict__ Qh, const _Float16* __restrict__ Ql,
                     const _Float16* __restrict__ Kh, const _Float16* __restrict__ Kl,
                     const float* __restrict__ kn, unsigned long long* __restrict__ out) {
    __shared__ __align__(16) char smem[33792];   // epilogue reduction only: [128][33] u64

    const int tid = (int)threadIdx.x;
    const int wave = tid >> 6, lane = tid & 63;
    const int l15 = lane & 15, quad = lane >> 4;

    // XCD-aware swizzle: blockIdx%8 == XCD (round-robin heuristic). Each XCD gets a
    // 16qt x 32kt rectangle => Q 1.28 MB + K 2.56 MB = 3.84 MB <= 4 MiB L2.
    const int b = (int)blockIdx.x;
    const int xcd = b & 7;
    const int i = b >> 3;                         // 0..511 within XCD
    const int qt = (xcd >> 1) * 16 + (i & 15);
    const int kt = (xcd & 1) * 32 + (i >> 4);

    const int mbase = (wave >> 1) * 64;           // wave tile: 64x64 within 128x128
    const int nbase = (wave & 1) * 64;
    const int q0 = qt * 128, n0 = kt * 128;

    // frag-linear global bases (all coalesced 16B/lane, L2-hot under the swizzle)
    const int agrp = (mbase >> 4);
    const int bgrp = (nbase >> 4);
    const _Float16* gQh = Qh + (qt * 8 + agrp) * 512 + lane * 8;
    const _Float16* gQl = Ql + (qt * 8 + agrp) * 512 + lane * 8;
    const _Float16* gKh = Kh + (kt * 8 + bgrp) * 512 + lane * 8;
    const _Float16* gKl = Kl + (kt * 8 + bgrp) * 512 + lane * 8;

    f32x4 acc[4][4];                              // single merged accumulator: 64 AGPR
#pragma unroll
    for (int ii = 0; ii < 4; ++ii)
#pragma unroll
        for (int j = 0; j < 4; ++j)
            acc[ii][j] = (f32x4)0.f;

    // 2-deep fragment double-buffer; chunk loop fully unrolled => all indices static.
    half8 ah[2][4], al[2][4], bh[2][4], bl[2][4];
#pragma unroll
    for (int mt = 0; mt < 4; ++mt) {
        ah[0][mt] = *(const half8*)(gQh + mt * 512);
        al[0][mt] = *(const half8*)(gQl + mt * 512);
    }
#pragma unroll
    for (int nt = 0; nt < 4; ++nt) {
        bh[0][nt] = *(const half8*)(gKh + nt * 512);
        bl[0][nt] = *(const half8*)(gKl + nt * 512);
    }

#pragma unroll
    for (int c = 0; c < NCH; ++c) {
        const int cur = c & 1, nxt = cur ^ 1;
        if (c + 1 < NCH) {   // issue next chunk's 16 loads BEFORE this chunk's MFMA block
#pragma unroll
            for (int mt = 0; mt < 4; ++mt) {
                ah[nxt][mt] = *(const half8*)(gQh + (c + 1) * CST + mt * 512);
                al[nxt][mt] = *(const half8*)(gQl + (c + 1) * CST + mt * 512);
            }
#pragma unroll
            for (int nt = 0; nt < 4; ++nt) {
                bh[nxt][nt] = *(const half8*)(gKh + (c + 1) * CST + nt * 512);
                bl[nxt][nt] = *(const half8*)(gKl + (c + 1) * CST + nt * 512);
            }
        }

        __builtin_amdgcn_s_setprio(1);
#pragma unroll
        for (int nt = 0; nt < 4; ++nt) {
#pragma unroll
            for (int mt = 0; mt < 4; ++mt) {
                acc[mt][nt] = __builtin_amdgcn_mfma_f32_16x16x32_f16(ah[cur][mt], bh[cur][nt], acc[mt][nt], 0, 0, 0);
                acc[mt][nt] = __builtin_amdgcn_mfma_f32_16x16x32_f16(ah[cur][mt], bl[cur][nt], acc[mt][nt], 0, 0, 0);
                acc[mt][nt] = __builtin_amdgcn_mfma_f32_16x16x32_f16(al[cur][mt], bh[cur][nt], acc[mt][nt], 0, 0, 0);
            }
        }
        __builtin_amdgcn_s_setprio(0);
    }

    // epilogue: dist = kn - 2*acc; per-lane argmin over its 4 columns.
    // Pack (value,idx) into order-preserving u64: lexicographic u64-min == tie rule.
    float knv[4];
    int nglob[4];
#pragma unroll
    for (int nt = 0; nt < 4; ++nt) {
        nglob[nt] = n0 + nbase + nt * 16 + l15;
        knv[nt] = kn[nglob[nt]];
    }
    unsigned long long* redu = (unsigned long long*)smem;   // [128][33] u64 (33.8 KiB)

#pragma unroll
    for (int mt = 0; mt < 4; ++mt)
#pragma unroll
        for (int r = 0; r < 4; ++r) {
            float bv = 1e38f;
            int bn = 0x7fffffff;
#pragma unroll
            for (int nt = 0; nt < 4; ++nt) {   // ascending n within lane -> strict < ok
                float d = knv[nt] - 2.0f * acc[mt][nt][r];
                if (d < bv) { bv = d; bn = nglob[nt]; }
            }
            int m = mbase + mt * 16 + quad * 4 + r;        // C layout: row = quad*4 + reg
            int cidx = (nbase >> 2) + l15;                 // 0..31
            unsigned u = __float_as_uint(bv);
            u = (u & 0x80000000u) ? ~u : (u | 0x80000000u);   // order-preserving map
            redu[m * 33 + cidx] = ((unsigned long long)u << 32) | (unsigned)bn;
        }
    __syncthreads();

    {   // all 256 threads: 2 per row, 16 u64-min each, pair-combine via shfl
        int row = tid >> 1;
        int base = (tid & 1) * 16;
        unsigned long long best = 0xFFFFFFFFFFFFFFFFull;
        const unsigned long long* rp = redu + row * 33 + base;
#pragma unroll
        for (int t2 = 0; t2 < 16; ++t2) {
            unsigned long long v = rp[t2];
            best = (v < best) ? v : best;
        }
        unsigned long long other = __shfl_xor(best, 1, 64);
        best = (other < best) ? other : best;
        if (!(tid & 1)) atomicMin(&out[q0 + row], best);
    }
}

// ---------------- gather + fold (overlap-add mean) ----------------
// 8 lanes per output pixel: lane-slot s=0..6 handles patch-row i=s (7 j-loads, ILP 7),
// s=7 idle; shfl_down(width=8) tree reduces; s==0 divides by ANALYTIC count and stores.
// 864 blocks x 256 = 13.5 waves/CU.
__global__ void k_fold(const float* __restrict__ value,
                       const unsigned long long* __restrict__ fidx64,
                       float* __restrict__ out) {
    int t = blockIdx.x * 256 + threadIdx.x;   // 3*96*96*8 = 221184
    int pix = t >> 3, s = t & 7;
    if (pix >= 3 * IMG * IMG) return;
    int c = pix / (IMG * IMG);
    int rem = pix % (IMG * IMG);
    int Y = rem / IMG, X = rem % IMG;

    float partial = 0.f;
    int yy = Y - s;
    if (s < 7 && (unsigned)yy < (unsigned)HO) {
        const unsigned* fidx32 = (const unsigned*)fidx64;   // low word = row index
        const float* vbase = value + c * 49 + s * 7;
        int rows[7];
        bool oks[7];
#pragma unroll
        for (int j = 0; j < 7; ++j) {
            int xx = X - j;
            bool ok = (unsigned)xx < (unsigned)HO;
            int p = ok ? (yy * HO + xx) : 0;
            rows[j] = (int)fidx32[2 * p];
            oks[j] = ok;
        }
#pragma unroll
        for (int j = 0; j < 7; ++j) {
            float v = vbase[rows[j] * DD + j];   // always in-bounds (row 0 when masked)
            if (oks[j]) partial += v;
        }
    }
    partial += __shfl_down(partial, 4, 8);
    partial += __shfl_down(partial, 2, 8);
    partial += __shfl_down(partial, 1, 8);
    if (s == 0) {
        int i0 = max(0, Y - (HO - 1)), i1 = min(6, Y);
        int j0 = max(0, X - (HO - 1)), j1 = min(6, X);
        float cnt = (float)((i1 - i0 + 1) * (j1 - j0 + 1));
        out[pix] = partial / cnt;
    }
}

extern "C" void kernel_launch(void* const* d_in, const int* in_sizes, int n_in,
                              void* d_out, int out_size, void* d_ws, size_t ws_size,
                              hipStream_t stream) {
    const float* query = (const float*)d_in[0];
    const float* key   = (const float*)d_in[1];
    const float* value = (const float*)d_in[2];
    float* out = (float*)d_out;

    _Float16* Qh = (_Float16*)d_ws;           // ARRN f16 each
    _Float16* Ql = Qh + ARRN;
    _Float16* Kh = Ql + ARRN;
    _Float16* Kl = Kh + ARRN;
    float* kn = (float*)(Kl + ARRN);          // 8192 f32
    unsigned long long* fidx64 = (unsigned long long*)(kn + 8192);   // 8192 u64

    dim3 gp(768, 2);   // 640 split blocks + 128 fused-kn blocks (y==1)
    k_prep<<<gp, 256, 0, stream>>>(query, key, Qh, Ql, Kh, Kl, kn, fidx64);
    k_nn<<<4096, 256, 0, stream>>>(Qh, Ql, Kh, Kl, kn, fidx64);
    k_fold<<<864, 256, 0, stream>>>(value, fidx64, out);
}

// Round 9
// 143.598 us; speedup vs baseline: 1.0115x; 1.0115x over previous
//
#include <hip/hip_runtime.h>

// TorchPatchNN: unfold(7x7) -> NN argmin over 8100 keys (D=147) -> gather value -> fold mean.
// Round 14: occupancy-3 at constant tile. R13 post-mortem: merged acc landed (104 VGPR +
//  64 AGPR) but the frag dbuf was folded by the compiler (VGPR fell 124->104, dur flat).
//  Per-SIMD accounting (19.4 cyc per 16x16x32 f16 MFMA): MFMA pipe 43%, VALU 27%, waits 30%
//  at 2 waves/SIMD -- stalls have no coverage. 168 regs/wave is exactly at the 3-wave line
//  (512/168=3.04); R10 proved 3 blocks/CU schedulable at 136 regs. So: keep the 128x128
//  tile (R10's regression was the halved tile, not occupancy), drop the folded dbuf,
//  __launch_bounds__(256,3) to pull the allocator under the line. 3 blocks/CU = +50% TLP,
//  un-barriered waves stagger naturally.
//  Keep: merged-acc scheme (lo-planes UNSCALED, 3 passes into one acc, epilogue kn-2*acc),
//  barrier-free K-loop, XCD swizzle, setprio, u64 epilogue, R11 k_fold, R13 k_prep.
//  Falsifier A: occupancy ~20% => HW reg granule 16 blocks 3 waves => next: 32x32x16 shape.
//  Falsifier B: occupancy up, dur flat => TLP not the bind => epilogue ablation next.

#define NQ 8100
#define NK 8100
#define DD 147
#define HO 90
#define IMG 96
#define NCH 5                 // K chunks of 32 (160 padded K)
#define CST 262144            // f16 per chunk plane: 512 groups x 512
#define ARRN (NCH * CST)      // f16 per array

typedef _Float16 half8 __attribute__((ext_vector_type(8)));
typedef float f32x4 __attribute__((ext_vector_type(4)));

// ---------------- prep: split Q/K into fp16 hi/lo (frag order) + key norms + init ---------
__global__ void k_prep(const float* __restrict__ query, const float* __restrict__ key,
                       _Float16* __restrict__ Qh, _Float16* __restrict__ Ql,
                       _Float16* __restrict__ Kh, _Float16* __restrict__ Kl,
                       float* __restrict__ kn, unsigned long long* __restrict__ fidx64) {
    const int bx = blockIdx.x;
    const bool isK = (blockIdx.y != 0);

    if (bx >= 640) {                      // fused k_kn region: 128 blocks on y==1
        if (!isK) return;
        int wave = threadIdx.x >> 6, lane = threadIdx.x & 63;
        int kb = ((bx - 640) * 4 + wave) * 16;
        for (int r = 0; r < 16; ++r) {
            int k = kb + r;
            float s = 0.f;
            if (k < NK)
                for (int d = lane; d < DD; d += 64) {
                    float v = key[k * DD + d];
                    s += v * v;
                }
#pragma unroll
            for (int off = 32; off; off >>= 1) s += __shfl_down(s, off, 64);
            if (lane == 0) {
                kn[k] = (k < NK) ? s : 1e30f;
                fidx64[k] = 0xFFFFFFFFFFFFFFFFull;   // ws re-poisoned every launch
            }
        }
        return;
    }

    int t = bx * 256 + threadIdx.x;             // 0 .. 163839 (ARRN/8)
    int c = t >> 15;                            // chunk
    int rem = t & 32767;                        // g*64 + lane
    int col = ((rem >> 6) << 4) + (rem & 15);   // g*16 + l15
    int quad = (rem >> 4) & 3;
    int kbase = c * 32 + quad * 8;

    float v[8];
#pragma unroll
    for (int j = 0; j < 8; ++j) {
        int k = kbase + j;
        float x = 0.f;
        if (k < DD && col < NQ) {
            if (isK) {
                x = key[col * DD + k];
            } else {
                int c3 = k / 49, r2 = k - 49 * c3;
                int rr = r2 / 7, ss = r2 - 7 * rr;
                int y = col / HO, xx = col - HO * y;
                x = query[(c3 * IMG + y + rr) * IMG + xx + ss];
            }
        }
        v[j] = x;
    }
    half8 h8, l8;
#pragma unroll
    for (int j = 0; j < 8; ++j) {
        _Float16 h = (_Float16)v[j];
        h8[j] = h;
        l8[j] = (_Float16)(v[j] - (float)h);   // UNSCALED lo (merged-acc scheme)
    }
    if (isK) {
        *(half8*)(Kh + t * 8) = h8;
        *(half8*)(Kl + t * 8) = l8;
    } else {
        *(half8*)(Qh + t * 8) = h8;
        *(half8*)(Ql + t * 8) = l8;
    }
}

// ---------------- main: merged-acc split-f16 MFMA Q.K^T + fused argmin ----------------
// Barrier-free K-loop, single-buffer frags, single acc[4][4], 3 blocks/CU target.
__launch_bounds__(256, 3)
__global__ void k_nn(const _Float16* __restrict__ Qh, const _Float16* __restrict__ Ql,
                     const _Float16* __restrict__ Kh, const _Float16* __restrict__ Kl,
                     const float* __restrict__ kn, unsigned long long* __restrict__ out) {
    __shared__ __align__(16) char smem[33792];   // epilogue reduction only: [128][33] u64

    const int tid = (int)threadIdx.x;
    const int wave = tid >> 6, lane = tid & 63;
    const int l15 = lane & 15, quad = lane >> 4;

    // XCD-aware swizzle: blockIdx%8 == XCD (round-robin heuristic). Each XCD gets a
    // 16qt x 32kt rectangle => Q 1.28 MB + K 2.56 MB = 3.84 MB <= 4 MiB L2.
    const int b = (int)blockIdx.x;
    const int xcd = b & 7;
    const int i = b >> 3;                         // 0..511 within XCD
    const int qt = (xcd >> 1) * 16 + (i & 15);
    const int kt = (xcd & 1) * 32 + (i >> 4);

    const int mbase = (wave >> 1) * 64;           // wave tile: 64x64 within 128x128
    const int nbase = (wave & 1) * 64;
    const int q0 = qt * 128, n0 = kt * 128;

    // frag-linear global bases (all coalesced 16B/lane, L2-hot under the swizzle)
    const int agrp = (mbase >> 4);
    const int bgrp = (nbase >> 4);
    const _Float16* gQh = Qh + (qt * 8 + agrp) * 512 + lane * 8;
    const _Float16* gQl = Ql + (qt * 8 + agrp) * 512 + lane * 8;
    const _Float16* gKh = Kh + (kt * 8 + bgrp) * 512 + lane * 8;
    const _Float16* gKl = Kl + (kt * 8 + bgrp) * 512 + lane * 8;

    f32x4 acc[4][4];                              // single merged accumulator: 64 AGPR
#pragma unroll
    for (int ii = 0; ii < 4; ++ii)
#pragma unroll
        for (int j = 0; j < 4; ++j)
            acc[ii][j] = (f32x4)0.f;

#pragma unroll
    for (int c = 0; c < NCH; ++c) {
        // 16 independent coalesced loads; no barrier anywhere in the K-loop.
        half8 ah[4], al[4], bh[4], bl[4];
#pragma unroll
        for (int mt = 0; mt < 4; ++mt) {
            ah[mt] = *(const half8*)(gQh + c * CST + mt * 512);
            al[mt] = *(const half8*)(gQl + c * CST + mt * 512);
        }
#pragma unroll
        for (int nt = 0; nt < 4; ++nt) {
            bh[nt] = *(const half8*)(gKh + c * CST + nt * 512);
            bl[nt] = *(const half8*)(gKl + c * CST + nt * 512);
        }

        __builtin_amdgcn_s_setprio(1);
#pragma unroll
        for (int nt = 0; nt < 4; ++nt) {
#pragma unroll
            for (int mt = 0; mt < 4; ++mt) {
                acc[mt][nt] = __builtin_amdgcn_mfma_f32_16x16x32_f16(ah[mt], bh[nt], acc[mt][nt], 0, 0, 0);
                acc[mt][nt] = __builtin_amdgcn_mfma_f32_16x16x32_f16(ah[mt], bl[nt], acc[mt][nt], 0, 0, 0);
                acc[mt][nt] = __builtin_amdgcn_mfma_f32_16x16x32_f16(al[mt], bh[nt], acc[mt][nt], 0, 0, 0);
            }
        }
        __builtin_amdgcn_s_setprio(0);
    }

    // epilogue: dist = kn - 2*acc; per-lane argmin over its 4 columns.
    // Pack (value,idx) into order-preserving u64: lexicographic u64-min == tie rule.
    float knv[4];
    int nglob[4];
#pragma unroll
    for (int nt = 0; nt < 4; ++nt) {
        nglob[nt] = n0 + nbase + nt * 16 + l15;
        knv[nt] = kn[nglob[nt]];
    }
    unsigned long long* redu = (unsigned long long*)smem;   // [128][33] u64 (33.8 KiB)

#pragma unroll
    for (int mt = 0; mt < 4; ++mt)
#pragma unroll
        for (int r = 0; r < 4; ++r) {
            float bv = 1e38f;
            int bn = 0x7fffffff;
#pragma unroll
            for (int nt = 0; nt < 4; ++nt) {   // ascending n within lane -> strict < ok
                float d = knv[nt] - 2.0f * acc[mt][nt][r];
                if (d < bv) { bv = d; bn = nglob[nt]; }
            }
            int m = mbase + mt * 16 + quad * 4 + r;        // C layout: row = quad*4 + reg
            int cidx = (nbase >> 2) + l15;                 // 0..31
            unsigned u = __float_as_uint(bv);
            u = (u & 0x80000000u) ? ~u : (u | 0x80000000u);   // order-preserving map
            redu[m * 33 + cidx] = ((unsigned long long)u << 32) | (unsigned)bn;
        }
    __syncthreads();

    {   // all 256 threads: 2 per row, 16 u64-min each, pair-combine via shfl
        int row = tid >> 1;
        int base = (tid & 1) * 16;
        unsigned long long best = 0xFFFFFFFFFFFFFFFFull;
        const unsigned long long* rp = redu + row * 33 + base;
#pragma unroll
        for (int t2 = 0; t2 < 16; ++t2) {
            unsigned long long v = rp[t2];
            best = (v < best) ? v : best;
        }
        unsigned long long other = __shfl_xor(best, 1, 64);
        best = (other < best) ? other : best;
        if (!(tid & 1)) atomicMin(&out[q0 + row], best);
    }
}

// ---------------- gather + fold (overlap-add mean) ----------------
// 8 lanes per output pixel: lane-slot s=0..6 handles patch-row i=s (7 j-loads, ILP 7),
// s=7 idle; shfl_down(width=8) tree reduces; s==0 divides by ANALYTIC count and stores.
// 864 blocks x 256 = 13.5 waves/CU.
__global__ void k_fold(const float* __restrict__ value,
                       const unsigned long long* __restrict__ fidx64,
                       float* __restrict__ out) {
    int t = blockIdx.x * 256 + threadIdx.x;   // 3*96*96*8 = 221184
    int pix = t >> 3, s = t & 7;
    if (pix >= 3 * IMG * IMG) return;
    int c = pix / (IMG * IMG);
    int rem = pix % (IMG * IMG);
    int Y = rem / IMG, X = rem % IMG;

    float partial = 0.f;
    int yy = Y - s;
    if (s < 7 && (unsigned)yy < (unsigned)HO) {
        const unsigned* fidx32 = (const unsigned*)fidx64;   // low word = row index
        const float* vbase = value + c * 49 + s * 7;
        int rows[7];
        bool oks[7];
#pragma unroll
        for (int j = 0; j < 7; ++j) {
            int xx = X - j;
            bool ok = (unsigned)xx < (unsigned)HO;
            int p = ok ? (yy * HO + xx) : 0;
            rows[j] = (int)fidx32[2 * p];
            oks[j] = ok;
        }
#pragma unroll
        for (int j = 0; j < 7; ++j) {
            float v = vbase[rows[j] * DD + j];   // always in-bounds (row 0 when masked)
            if (oks[j]) partial += v;
        }
    }
    partial += __shfl_down(partial, 4, 8);
    partial += __shfl_down(partial, 2, 8);
    partial += __shfl_down(partial, 1, 8);
    if (s == 0) {
        int i0 = max(0, Y - (HO - 1)), i1 = min(6, Y);
        int j0 = max(0, X - (HO - 1)), j1 = min(6, X);
        float cnt = (float)((i1 - i0 + 1) * (j1 - j0 + 1));
        out[pix] = partial / cnt;
    }
}

extern "C" void kernel_launch(void* const* d_in, const int* in_sizes, int n_in,
                              void* d_out, int out_size, void* d_ws, size_t ws_size,
                              hipStream_t stream) {
    const float* query = (const float*)d_in[0];
    const float* key   = (const float*)d_in[1];
    const float* value = (const float*)d_in[2];
    float* out = (float*)d_out;

    _Float16* Qh = (_Float16*)d_ws;           // ARRN f16 each
    _Float16* Ql = Qh + ARRN;
    _Float16* Kh = Ql + ARRN;
    _Float16* Kl = Kh + ARRN;
    float* kn = (float*)(Kl + ARRN);          // 8192 f32
    unsigned long long* fidx64 = (unsigned long long*)(kn + 8192);   // 8192 u64

    dim3 gp(768, 2);   // 640 split blocks + 128 fused-kn blocks (y==1)
    k_prep<<<gp, 256, 0, stream>>>(query, key, Qh, Ql, Kh, Kl, kn, fidx64);
    k_nn<<<4096, 256, 0, stream>>>(Qh, Ql, Kh, Kl, kn, fidx64);
    k_fold<<<864, 256, 0, stream>>>(value, fidx64, out);
}